// Round 1
// baseline (1522.947 us; speedup 1.0000x reference)
//
#include <hip/hip_runtime.h>

// GRUModule: MLP(64->128->128,ELU) -> xg=W_ih proj -> GRU(H=128) w/ reset -> W_out head
// B=128, T=1024. All GEMMs via mfma_f32_16x16x32_bf16.
// ws layout: [xg bf16: 100,663,296 B][y bf16: 33,554,432 B]  (128 MiB total)

#define T_SZ 1024

typedef __attribute__((ext_vector_type(8))) short short8;
typedef __attribute__((ext_vector_type(4))) float f32x4;

__device__ __forceinline__ unsigned short f2b(float f){
  unsigned int u = __builtin_bit_cast(unsigned int, f);
  u += 0x7fffu + ((u >> 16) & 1u);
  return (unsigned short)(u >> 16);
}
__device__ __forceinline__ float b2f(unsigned int hs){
  unsigned int u = hs << 16;
  return __builtin_bit_cast(float, u);
}
__device__ __forceinline__ short8 load_w8(const float* __restrict__ p){
  const float4* q = (const float4*)p;
  float4 u0 = q[0], u1 = q[1];
  short8 v;
  v[0]=(short)f2b(u0.x); v[1]=(short)f2b(u0.y); v[2]=(short)f2b(u0.z); v[3]=(short)f2b(u0.w);
  v[4]=(short)f2b(u1.x); v[5]=(short)f2b(u1.y); v[6]=(short)f2b(u1.z); v[7]=(short)f2b(u1.w);
  return v;
}
__device__ __forceinline__ float elu(float v){ return v > 0.f ? v : __expf(v) - 1.f; }
__device__ __forceinline__ float sigm(float x){ return 1.f / (1.f + __expf(-x)); }
__device__ __forceinline__ float tanh_fast(float x){
  x = fminf(fmaxf(x, -15.f), 15.f);
  float e = __expf(-2.f * x);
  return (1.f - e) / (1.f + e);
}
#define MFMA16(a,b,c) __builtin_amdgcn_mfma_f32_16x16x32_bf16(a, b, c, 0, 0, 0)

// ---------------------------------------------------------------------------
// K1: fused MLP1 + MLP2 + W_ih projection. M-tile = (t, g): rows b=16g..16g+15.
// xg output layout: shorts, slot = ((t*8+g)*8 + wave)*64 + lane, 12 shorts/slot
// idx = gate*4 + r  holds  xg[b=16g+quad*4+r][t][n=16*wave+col+128*gate] + b_ih
// ---------------------------------------------------------------------------
__global__ __launch_bounds__(512) void fused_mlp(
    const float* __restrict__ x,
    const float* __restrict__ W1, const float* __restrict__ b1,
    const float* __restrict__ W2, const float* __restrict__ b2,
    const float* __restrict__ Wih, const float* __restrict__ bih,
    unsigned short* __restrict__ xg)
{
  __shared__ unsigned short xl[16*72];     // x tile, A-layout [16][64+8]
  __shared__ unsigned short h1l[16*136];   // h1 tile [16][128+8]
  __shared__ unsigned short h2l[16*136];   // h2 tile [16][128+8]
  const int tid = threadIdx.x;
  const int wv = tid >> 6, l = tid & 63, quad = l >> 4, col = l & 15;
  const int n = 16*wv + col;

  short8 w1f[2], w2f[4], wif[3][4];
  #pragma unroll
  for(int ks=0; ks<2; ks++) w1f[ks] = load_w8(W1 + n*64  + ks*32 + quad*8);
  #pragma unroll
  for(int ks=0; ks<4; ks++) w2f[ks] = load_w8(W2 + n*128 + ks*32 + quad*8);
  #pragma unroll
  for(int gt=0; gt<3; gt++){
    #pragma unroll
    for(int ks=0; ks<4; ks++)
      wif[gt][ks] = load_w8(Wih + (n + 128*gt)*128 + ks*32 + quad*8);
  }
  const float b1v = b1[n], b2v = b2[n];
  float bihv[3];
  #pragma unroll
  for(int gt=0; gt<3; gt++) bihv[gt] = bih[n + 128*gt];

  for(int tile = blockIdx.x; tile < 8192; tile += gridDim.x){
    const int t = tile >> 3, g = tile & 7;
    __syncthreads();
    // stage x tile: rows b = 16g+m (m=0..15), k<64
    for(int i = tid; i < 1024; i += 512){
      int m = i >> 6, k = i & 63;
      xl[m*72 + k] = f2b(x[(size_t)(16*g + m)*(T_SZ*64) + (size_t)t*64 + k]);
    }
    __syncthreads();
    // GEMM1 + ELU
    f32x4 acc1 = {b1v, b1v, b1v, b1v};
    #pragma unroll
    for(int ks=0; ks<2; ks++){
      short8 a = *(const short8*)&xl[col*72 + ks*32 + quad*8];
      acc1 = MFMA16(a, w1f[ks], acc1);
    }
    #pragma unroll
    for(int r=0; r<4; r++)
      h1l[(quad*4+r)*136 + n] = f2b(elu(acc1[r]));
    __syncthreads();
    // GEMM2 + ELU
    f32x4 acc2 = {b2v, b2v, b2v, b2v};
    #pragma unroll
    for(int ks=0; ks<4; ks++){
      short8 a = *(const short8*)&h1l[col*136 + ks*32 + quad*8];
      acc2 = MFMA16(a, w2f[ks], acc2);
    }
    #pragma unroll
    for(int r=0; r<4; r++)
      h2l[(quad*4+r)*136 + n] = f2b(elu(acc2[r]));
    __syncthreads();
    // GEMM3 (3 gate N-tiles per wave)
    f32x4 a0 = {bihv[0], bihv[0], bihv[0], bihv[0]};
    f32x4 a1 = {bihv[1], bihv[1], bihv[1], bihv[1]};
    f32x4 a2 = {bihv[2], bihv[2], bihv[2], bihv[2]};
    #pragma unroll
    for(int ks=0; ks<4; ks++){
      short8 a = *(const short8*)&h2l[col*136 + ks*32 + quad*8];
      a0 = MFMA16(a, wif[0][ks], a0);
      a1 = MFMA16(a, wif[1][ks], a1);
      a2 = MFMA16(a, wif[2][ks], a2);
    }
    unsigned short* dst = xg + ((size_t)(tile*8 + wv)*64 + l)*12;
    unsigned int p6[6];
    p6[0] = (unsigned)f2b(a0[0]) | ((unsigned)f2b(a0[1]) << 16);
    p6[1] = (unsigned)f2b(a0[2]) | ((unsigned)f2b(a0[3]) << 16);
    p6[2] = (unsigned)f2b(a1[0]) | ((unsigned)f2b(a1[1]) << 16);
    p6[3] = (unsigned)f2b(a1[2]) | ((unsigned)f2b(a1[3]) << 16);
    p6[4] = (unsigned)f2b(a2[0]) | ((unsigned)f2b(a2[1]) << 16);
    p6[5] = (unsigned)f2b(a2[2]) | ((unsigned)f2b(a2[3]) << 16);
    uint2* d2 = (uint2*)dst;  // lane*24 B -> 8-byte aligned
    d2[0] = make_uint2(p6[0], p6[1]);
    d2[1] = make_uint2(p6[2], p6[3]);
    d2[2] = make_uint2(p6[4], p6[5]);
  }
}

// ---------------------------------------------------------------------------
// K2: GRU scan. 8 blocks (g = batch group of 16), 512 thr = 8 waves.
// Wave wv owns gate columns i = 16wv+col (tiles wv, wv+8, wv+16 => r,z,n align
// per-lane). h: LDS A-layout bf16 [16][128+8] + fp32 C-layout register copy.
// y written bf16 as [t][g][16][128] (out_gemm A-tiles). hT fp32 at t=1023.
// ---------------------------------------------------------------------------
__global__ __launch_bounds__(512) void gru_scan(
    const unsigned short* __restrict__ xg,
    const float* __restrict__ hx, const int* __restrict__ is_init,
    const float* __restrict__ Whh, const float* __restrict__ bhh,
    unsigned short* __restrict__ ys, float* __restrict__ hT)
{
  __shared__ unsigned short hl[16*136];
  const int tid = threadIdx.x;
  const int g = blockIdx.x;
  const int wv = tid >> 6, l = tid & 63, quad = l >> 4, col = l & 15;

  short8 whf[3][4];
  float bhv[3];
  #pragma unroll
  for(int gt=0; gt<3; gt++){
    int n = 16*wv + col + 128*gt;
    bhv[gt] = bhh[n];
    #pragma unroll
    for(int ks=0; ks<4; ks++)
      whf[gt][ks] = load_w8(Whh + n*128 + ks*32 + quad*8);
  }

  // init h0 = hx * (1 - m0)
  float hreg[4];
  #pragma unroll
  for(int r=0; r<4; r++){
    int b = 16*g + quad*4 + r;
    float h0 = hx[b*128 + 16*wv + col];
    float m0 = (float)is_init[(size_t)b * T_SZ];
    h0 *= (1.f - m0);
    hreg[r] = h0;
    hl[(quad*4+r)*136 + 16*wv + col] = f2b(h0);
  }

  const size_t xstride = (size_t)8*8*64*12;  // shorts per t
  const unsigned short* xbase = xg + ((size_t)(g*8 + wv)*64 + l)*12;
  unsigned int xc[6];
  { const uint2* q = (const uint2*)xbase;
    uint2 a = q[0], bq = q[1], c = q[2];
    xc[0]=a.x; xc[1]=a.y; xc[2]=bq.x; xc[3]=bq.y; xc[4]=c.x; xc[5]=c.y; }

  for(int t = 0; t < T_SZ; t++){
    const int tn = (t+1 < T_SZ) ? t+1 : T_SZ-1;
    const float msel = (t+1 < T_SZ) ? 1.f : 0.f;
    // prefetch xg(t+1) and reset masks m(t+1)
    unsigned int xn[6];
    { const uint2* q = (const uint2*)(xbase + (size_t)tn * xstride);
      uint2 a = q[0], bq = q[1], c = q[2];
      xn[0]=a.x; xn[1]=a.y; xn[2]=bq.x; xn[3]=bq.y; xn[4]=c.x; xn[5]=c.y; }
    float mn[4];
    #pragma unroll
    for(int r=0; r<4; r++){
      int b = 16*g + quad*4 + r;
      mn[r] = msel * (float)is_init[(size_t)b * T_SZ + tn];
    }
    __syncthreads();                         // h writes (t-1) visible
    short8 af[4];
    #pragma unroll
    for(int ks=0; ks<4; ks++)
      af[ks] = *(const short8*)&hl[col*136 + ks*32 + quad*8];
    __syncthreads();                         // all reads done before h rewrite
    f32x4 ar = {bhv[0], bhv[0], bhv[0], bhv[0]};
    f32x4 az = {bhv[1], bhv[1], bhv[1], bhv[1]};
    f32x4 an = {bhv[2], bhv[2], bhv[2], bhv[2]};
    #pragma unroll
    for(int ks=0; ks<4; ks++){
      ar = MFMA16(af[ks], whf[0][ks], ar);
      az = MFMA16(af[ks], whf[1][ks], az);
      an = MFMA16(af[ks], whf[2][ks], an);
    }
    #pragma unroll
    for(int r=0; r<4; r++){
      float xrv = b2f((xc[    (r>>1)] >> ((r&1)*16)) & 0xffffu);
      float xzv = b2f((xc[2 + (r>>1)] >> ((r&1)*16)) & 0xffffu);
      float xnv = b2f((xc[4 + (r>>1)] >> ((r&1)*16)) & 0xffffu);
      float rr = sigm(xrv + ar[r]);
      float zz = sigm(xzv + az[r]);
      float nn = tanh_fast(xnv + rr*an[r]);
      float hnew = (1.f - zz)*nn + zz*hreg[r];
      ys[((size_t)(t*8+g)*16 + quad*4 + r)*128 + 16*wv + col] = f2b(hnew);
      if(t == T_SZ-1)
        hT[(16*g + quad*4 + r)*128 + 16*wv + col] = hnew;
      hnew *= (1.f - mn[r]);                 // fold reset for step t+1
      hreg[r] = hnew;
      hl[(quad*4+r)*136 + 16*wv + col] = f2b(hnew);
    }
    #pragma unroll
    for(int i=0; i<6; i++) xc[i] = xn[i];
  }
}

// ---------------------------------------------------------------------------
// K3: out = y @ W_out.T + b_out.  A-tiles read straight from ys global.
// ---------------------------------------------------------------------------
__global__ __launch_bounds__(256) void out_gemm(
    const unsigned short* __restrict__ ys,
    const float* __restrict__ Wout, const float* __restrict__ bout,
    float* __restrict__ outp)
{
  const int tid = threadIdx.x;
  const int wv = tid >> 6, l = tid & 63, quad = l >> 4, col = l & 15;
  const int n = 16*wv + col;                 // d < 64
  short8 wof[4];
  #pragma unroll
  for(int ks=0; ks<4; ks++) wof[ks] = load_w8(Wout + n*128 + ks*32 + quad*8);
  const float bov = bout[n];
  for(int tile = blockIdx.x; tile < 8192; tile += gridDim.x){
    const int t = tile >> 3, g = tile & 7;
    const unsigned short* yt = ys + (size_t)tile * 16 * 128;
    f32x4 acc = {bov, bov, bov, bov};
    #pragma unroll
    for(int ks=0; ks<4; ks++){
      short8 a = *(const short8*)&yt[col*128 + ks*32 + quad*8];
      acc = MFMA16(a, wof[ks], acc);
    }
    #pragma unroll
    for(int r=0; r<4; r++)
      outp[(size_t)(16*g + quad*4 + r)*(T_SZ*64) + (size_t)t*64 + n] = acc[r];
  }
}

extern "C" void kernel_launch(void* const* d_in, const int* in_sizes, int n_in,
                              void* d_out, int out_size, void* d_ws, size_t ws_size,
                              hipStream_t stream)
{
  const float* x    = (const float*)d_in[0];
  const int*   ii   = (const int*)  d_in[1];   // is_init (bool -> int32 per harness)
  const float* hx   = (const float*)d_in[2];
  const float* W1   = (const float*)d_in[3];
  const float* b1   = (const float*)d_in[4];
  const float* W2   = (const float*)d_in[5];
  const float* b2   = (const float*)d_in[6];
  const float* Wih  = (const float*)d_in[7];
  const float* bih  = (const float*)d_in[8];
  const float* Whh  = (const float*)d_in[9];
  const float* bhh  = (const float*)d_in[10];
  const float* Wout = (const float*)d_in[11];
  const float* bout = (const float*)d_in[12];

  float* outp = (float*)d_out;
  float* hT   = outp + (size_t)128 * T_SZ * 64;

  unsigned short* xg = (unsigned short*)d_ws;                          // 100,663,296 B
  unsigned short* ys = (unsigned short*)((char*)d_ws + 100663296ull);  //  33,554,432 B

  fused_mlp<<<dim3(512), dim3(512), 0, stream>>>(x, W1, b1, W2, b2, Wih, bih, xg);
  gru_scan<<<dim3(8),   dim3(512), 0, stream>>>(xg, hx, ii, Whh, bhh, ys, hT);
  out_gemm<<<dim3(2048), dim3(256), 0, stream>>>(ys, Wout, bout, outp);
}

// Round 2
// 1148.124 us; speedup vs baseline: 1.3265x; 1.3265x over previous
//
#include <hip/hip_runtime.h>

// GRUModule: MLP(64->128->128,ELU) -> xg=W_ih proj -> segment-parallel GRU(H=128) -> W_out head
// B=128, T=1024. All GEMMs via mfma_f32_16x16x32_bf16.
// ws: [xg bf16 [b][t][384]: 100,663,296 B][ys bf16 [t][g][16][128]: 33,554,432 B] = 128 MiB
// ctrl+segs live in d_out (first ~540 KB), overwritten by out_gemm afterwards.

#define T_SZ 1024

typedef __attribute__((ext_vector_type(8))) short short8;
typedef __attribute__((ext_vector_type(4))) float f32x4;
typedef unsigned long long u64;
typedef unsigned int uint32;

__device__ __forceinline__ unsigned short f2b(float f){
  unsigned int u = __builtin_bit_cast(unsigned int, f);
  u += 0x7fffu + ((u >> 16) & 1u);
  return (unsigned short)(u >> 16);
}
__device__ __forceinline__ float b2f(unsigned int hs){
  unsigned int u = hs << 16;
  return __builtin_bit_cast(float, u);
}
__device__ __forceinline__ short8 load_w8(const float* __restrict__ p){
  const float4* q = (const float4*)p;
  float4 u0 = q[0], u1 = q[1];
  short8 v;
  v[0]=(short)f2b(u0.x); v[1]=(short)f2b(u0.y); v[2]=(short)f2b(u0.z); v[3]=(short)f2b(u0.w);
  v[4]=(short)f2b(u1.x); v[5]=(short)f2b(u1.y); v[6]=(short)f2b(u1.z); v[7]=(short)f2b(u1.w);
  return v;
}
__device__ __forceinline__ float elu(float v){ return v > 0.f ? v : __expf(v) - 1.f; }
__device__ __forceinline__ float sigm(float x){ return 1.f / (1.f + __expf(-x)); }
__device__ __forceinline__ float tanh_fast(float x){
  x = fminf(fmaxf(x, -15.f), 15.f);
  float e = __expf(-2.f * x);
  return (1.f - e) / (1.f + e);
}
#define MFMA16(a,b,c) __builtin_amdgcn_mfma_f32_16x16x32_bf16(a, b, c, 0, 0, 0)

// ctrl layout in d_out (as uint32*): [0]=n_segs [1]=n_tiles
// hist = C+16 (len 0..1024), cursor/base = C+2048, segs = C+4096 (<=131072)

// ---------------------------------------------------------------------------
__global__ __launch_bounds__(1024) void zero_ctrl(uint32* C){
  int i = blockIdx.x*1024 + threadIdx.x;
  if(i < 4096) C[i] = 0u;
}

// ---------------------------------------------------------------------------
// seg_pass: one wave per batch row. phase 0: histogram lengths. phase 1: place.
// ---------------------------------------------------------------------------
__global__ __launch_bounds__(512) void seg_pass(const int* __restrict__ ii, uint32* C, int phase){
  uint32* hist = C + 16;
  uint32* cur  = C + 2048;
  uint32* segs = C + 4096;
  const int wv = threadIdx.x >> 6, lane = threadIdx.x & 63;
  const int b = blockIdx.x*8 + wv;            // 16 blocks x 8 waves = 128 rows
  u64 bal[16];
  #pragma unroll
  for(int c=0;c<16;c++){
    int t = c*64 + lane;
    int m = ii[b*T_SZ + t];
    bal[c] = __ballot((m != 0) || (t == 0));
  }
  int fsA[16]; int nx = T_SZ;
  #pragma unroll
  for(int c=15;c>=0;c--){ fsA[c]=nx; if(bal[c]) nx = c*64 + __builtin_ctzll(bal[c]); }
  #pragma unroll
  for(int c=0;c<16;c++){
    if((bal[c] >> lane) & 1ull){
      int t = c*64 + lane;
      u64 hi = (lane < 63) ? (bal[c] >> (lane+1)) : 0ull;
      int nxt = hi ? (t + 1 + __builtin_ctzll(hi)) : fsA[c];
      int len = nxt - t;
      if(phase == 0) atomicAdd(hist + len, 1u);
      else {
        uint32 slot = atomicAdd(cur + len, 1u);
        segs[slot] = ((uint32)b << 21) | ((uint32)t << 11) | (uint32)len;
      }
    }
  }
}

// ---------------------------------------------------------------------------
// seg_prefix: exclusive prefix over lengths DESCENDING (len 1024 first) so the
// packed segs array is non-increasing in length -> tiles are length-uniform.
// ---------------------------------------------------------------------------
__global__ __launch_bounds__(1024) void seg_prefix(uint32* C){
  __shared__ uint32 s[1024];
  const int tid = threadIdx.x;
  const int len = 1024 - tid;                  // tid 0 <-> len 1024
  uint32* hist = C + 16;
  uint32* cur  = C + 2048;
  uint32 v = hist[len];
  s[tid] = v; __syncthreads();
  for(int off=1; off<1024; off<<=1){
    uint32 t = (tid >= off) ? s[tid-off] : 0u;
    __syncthreads();
    s[tid] += t;
    __syncthreads();
  }
  cur[len] = s[tid] - v;                       // exclusive base -> cursor
  if(tid == 1023){ C[0] = s[tid]; C[1] = (s[tid] + 15u) >> 4; }
}

// ---------------------------------------------------------------------------
// K1: fused MLP1 + MLP2 + W_ih projection. M-tile = (t, g): rows b=16g..16g+15.
// xg output: bf16 [b][t][384] via LDS transpose for coalesced 768B-row writes.
// ---------------------------------------------------------------------------
__global__ __launch_bounds__(512) void fused_mlp(
    const float* __restrict__ x,
    const float* __restrict__ W1, const float* __restrict__ b1,
    const float* __restrict__ W2, const float* __restrict__ b2,
    const float* __restrict__ Wih, const float* __restrict__ bih,
    unsigned short* __restrict__ xg)
{
  __shared__ unsigned short xl[16*72];     // x tile, A-layout [16][64+8]
  __shared__ unsigned short h1l[16*136];
  __shared__ unsigned short h2l[16*136];
  __shared__ unsigned short xgl[16*392];   // [16 rows][384+8] gate staging
  const int tid = threadIdx.x;
  const int wv = tid >> 6, l = tid & 63, quad = l >> 4, col = l & 15;
  const int n = 16*wv + col;

  short8 w1f[2], w2f[4], wif[3][4];
  #pragma unroll
  for(int ks=0; ks<2; ks++) w1f[ks] = load_w8(W1 + n*64  + ks*32 + quad*8);
  #pragma unroll
  for(int ks=0; ks<4; ks++) w2f[ks] = load_w8(W2 + n*128 + ks*32 + quad*8);
  #pragma unroll
  for(int gt=0; gt<3; gt++){
    #pragma unroll
    for(int ks=0; ks<4; ks++)
      wif[gt][ks] = load_w8(Wih + (n + 128*gt)*128 + ks*32 + quad*8);
  }
  const float b1v = b1[n], b2v = b2[n];
  float bihv[3];
  #pragma unroll
  for(int gt=0; gt<3; gt++) bihv[gt] = bih[n + 128*gt];

  for(int tile = blockIdx.x; tile < 8192; tile += gridDim.x){
    const int t = tile >> 3, g = tile & 7;
    __syncthreads();
    for(int i = tid; i < 1024; i += 512){
      int m = i >> 6, k = i & 63;
      xl[m*72 + k] = f2b(x[(size_t)(16*g + m)*(T_SZ*64) + (size_t)t*64 + k]);
    }
    __syncthreads();
    f32x4 acc1 = {b1v, b1v, b1v, b1v};
    #pragma unroll
    for(int ks=0; ks<2; ks++){
      short8 a = *(const short8*)&xl[col*72 + ks*32 + quad*8];
      acc1 = MFMA16(a, w1f[ks], acc1);
    }
    #pragma unroll
    for(int r=0; r<4; r++)
      h1l[(quad*4+r)*136 + n] = f2b(elu(acc1[r]));
    __syncthreads();
    f32x4 acc2 = {b2v, b2v, b2v, b2v};
    #pragma unroll
    for(int ks=0; ks<4; ks++){
      short8 a = *(const short8*)&h1l[col*136 + ks*32 + quad*8];
      acc2 = MFMA16(a, w2f[ks], acc2);
    }
    #pragma unroll
    for(int r=0; r<4; r++)
      h2l[(quad*4+r)*136 + n] = f2b(elu(acc2[r]));
    __syncthreads();
    f32x4 a0 = {bihv[0], bihv[0], bihv[0], bihv[0]};
    f32x4 a1 = {bihv[1], bihv[1], bihv[1], bihv[1]};
    f32x4 a2 = {bihv[2], bihv[2], bihv[2], bihv[2]};
    #pragma unroll
    for(int ks=0; ks<4; ks++){
      short8 a = *(const short8*)&h2l[col*136 + ks*32 + quad*8];
      a0 = MFMA16(a, wif[0][ks], a0);
      a1 = MFMA16(a, wif[1][ks], a1);
      a2 = MFMA16(a, wif[2][ks], a2);
    }
    #pragma unroll
    for(int r=0; r<4; r++){
      int row = quad*4 + r;
      xgl[row*392 +       n] = f2b(a0[r]);
      xgl[row*392 + 128 + n] = f2b(a1[r]);
      xgl[row*392 + 256 + n] = f2b(a2[r]);
    }
    __syncthreads();
    // cooperative coalesced write: 16 rows x 768 B
    {
      const int row = tid >> 5, k = tid & 31;
      unsigned short* dst = xg + ((size_t)(16*g + row)*T_SZ + t)*384;
      const unsigned short* srcl = xgl + row*392;
      #pragma unroll
      for(int i=0; i<3; i++)
        *(u64*)(dst + i*128 + k*4) = *(const u64*)(srcl + i*128 + k*4);
    }
  }
}

// ---------------------------------------------------------------------------
// K2: segment-parallel GRU. One block = tile of 16 segments (sorted desc len).
// 8 waves: wave wv owns hidden cols 16wv..16wv+15 for all 3 gates.
// xg rows gathered cooperatively into double-buffered LDS.
// ---------------------------------------------------------------------------
__global__ __launch_bounds__(512) void gru_seg_scan(
    const unsigned short* __restrict__ xg,
    const float* __restrict__ hx, const int* __restrict__ ii,
    const float* __restrict__ Whh, const float* __restrict__ bhh,
    const uint32* __restrict__ C,
    unsigned short* __restrict__ ys, float* __restrict__ hT)
{
  __shared__ unsigned short hl[16*136];          // h, A-layout
  __shared__ unsigned short xbuf[2][16*772];     // xg tile, [16 rows][768+4]
  __shared__ int srb[16], srt[16], srlen[16];
  const int tid = threadIdx.x;
  const int wv = tid >> 6, l = tid & 63, quad = l >> 4, col = l & 15;
  const int nidx = 16*wv + col;
  const int frow = tid >> 5, fk = tid & 31;      // fetch assignment

  const uint32 nsegs = C[0];
  const uint32 ntile = C[1];
  const uint32* segs = C + 4096;

  short8 whf[3][4];
  float bhv[3];
  #pragma unroll
  for(int gt=0; gt<3; gt++){
    int n = nidx + 128*gt;
    bhv[gt] = bhh[n];
    #pragma unroll
    for(int ks=0; ks<4; ks++)
      whf[gt][ks] = load_w8(Whh + n*128 + ks*32 + quad*8);
  }

  for(uint32 tile = blockIdx.x; tile < ntile; tile += gridDim.x){
    __syncthreads();                             // protect sr*/hl/xbuf reuse
    if(tid < 16){
      uint32 sidx = 16*tile + (uint32)tid;
      uint32 w = segs[16*tile];                  // row0 always valid
      uint32 ln = 0;
      if(sidx < nsegs){ w = segs[sidx]; ln = w & 2047u; }
      srb[tid] = (int)(w >> 21);
      srt[tid] = (int)((w >> 11) & 1023u);
      srlen[tid] = (int)ln;
    }
    __syncthreads();
    const int maxlen = srlen[0];                 // desc order -> row0 is max

    // h0: hx if segment starts at t=0 with no reset, else 0
    float hreg[4];
    #pragma unroll
    for(int r=0; r<4; r++){
      int row = quad*4 + r;
      int b = srb[row];
      bool uh = (srlen[row] > 0) && (srt[row] == 0) && (ii[b*T_SZ] == 0);
      float h0 = uh ? hx[b*128 + nidx] : 0.f;
      hreg[r] = h0;
      hl[row*136 + nidx] = f2b(h0);
    }
    // prologue: fetch xg rows for step 0 into xbuf[0]
    {
      const unsigned short* src = xg + ((size_t)srb[frow]*T_SZ + srt[frow])*384;
      unsigned short* xb = &xbuf[0][frow*772];
      #pragma unroll
      for(int i=0; i<3; i++)
        *(u64*)(xb + i*128 + fk*4) = *(const u64*)(src + i*128 + fk*4);
    }

    int cur = 0;
    for(int i=0; i<maxlen; i++){
      // prefetch step i+1 (clamped) into registers
      u64 p0, p1, p2;
      {
        int rl = srlen[frow];
        int tc = (i+1 < rl) ? i+1 : (rl > 0 ? rl-1 : 0);
        const unsigned short* src = xg + ((size_t)srb[frow]*T_SZ + (srt[frow] + tc))*384;
        p0 = *(const u64*)(src +       fk*4);
        p1 = *(const u64*)(src + 128 + fk*4);
        p2 = *(const u64*)(src + 256 + fk*4);
      }
      __syncthreads();                           // B1: hl(i) + xbuf[cur] ready
      short8 af[4];
      #pragma unroll
      for(int ks=0; ks<4; ks++)
        af[ks] = *(const short8*)&hl[col*136 + ks*32 + quad*8];
      __syncthreads();                           // B2: hl reads done
      f32x4 ar = {bhv[0], bhv[0], bhv[0], bhv[0]};
      f32x4 az = {bhv[1], bhv[1], bhv[1], bhv[1]};
      f32x4 an = {bhv[2], bhv[2], bhv[2], bhv[2]};
      #pragma unroll
      for(int ks=0; ks<4; ks++){
        ar = MFMA16(af[ks], whf[0][ks], ar);
        az = MFMA16(af[ks], whf[1][ks], az);
        an = MFMA16(af[ks], whf[2][ks], an);
      }
      const unsigned short* xb = &xbuf[cur][0];
      #pragma unroll
      for(int r=0; r<4; r++){
        int row = quad*4 + r;
        float xrv = b2f(xb[row*772 +       nidx]);
        float xzv = b2f(xb[row*772 + 128 + nidx]);
        float xnv = b2f(xb[row*772 + 256 + nidx]);
        float rr = sigm(xrv + ar[r]);
        float zz = sigm(xzv + az[r]);
        float nn = tanh_fast(xnv + rr*an[r]);
        float hnew = (1.f - zz)*nn + zz*hreg[r];
        int rl = srlen[row];
        if(i < rl){
          int b = srb[row], t = srt[row] + i;
          ys[((size_t)(t*8 + (b>>4))*16 + (b&15))*128 + nidx] = f2b(hnew);
          if(i == rl-1 && (srt[row] + rl) == T_SZ)
            hT[b*128 + nidx] = hnew;
        }
        hreg[r] = hnew;
        hl[row*136 + nidx] = f2b(hnew);
      }
      // drain prefetch into the other buffer
      {
        unsigned short* xb2 = &xbuf[cur^1][frow*772];
        *(u64*)(xb2 +       fk*4) = p0;
        *(u64*)(xb2 + 128 + fk*4) = p1;
        *(u64*)(xb2 + 256 + fk*4) = p2;
      }
      cur ^= 1;
    }
  }
}

// ---------------------------------------------------------------------------
// K3: out = y @ W_out.T + b_out.
// ---------------------------------------------------------------------------
__global__ __launch_bounds__(256) void out_gemm(
    const unsigned short* __restrict__ ys,
    const float* __restrict__ Wout, const float* __restrict__ bout,
    float* __restrict__ outp)
{
  const int tid = threadIdx.x;
  const int wv = tid >> 6, l = tid & 63, quad = l >> 4, col = l & 15;
  const int n = 16*wv + col;
  short8 wof[4];
  #pragma unroll
  for(int ks=0; ks<4; ks++) wof[ks] = load_w8(Wout + n*128 + ks*32 + quad*8);
  const float bov = bout[n];
  for(int tile = blockIdx.x; tile < 8192; tile += gridDim.x){
    const int t = tile >> 3, g = tile & 7;
    const unsigned short* yt = ys + (size_t)tile * 16 * 128;
    f32x4 acc = {bov, bov, bov, bov};
    #pragma unroll
    for(int ks=0; ks<4; ks++){
      short8 a = *(const short8*)&yt[col*128 + ks*32 + quad*8];
      acc = MFMA16(a, wof[ks], acc);
    }
    #pragma unroll
    for(int r=0; r<4; r++)
      outp[(size_t)(16*g + quad*4 + r)*(T_SZ*64) + (size_t)t*64 + n] = acc[r];
  }
}

extern "C" void kernel_launch(void* const* d_in, const int* in_sizes, int n_in,
                              void* d_out, int out_size, void* d_ws, size_t ws_size,
                              hipStream_t stream)
{
  const float* x    = (const float*)d_in[0];
  const int*   ii   = (const int*)  d_in[1];
  const float* hx   = (const float*)d_in[2];
  const float* W1   = (const float*)d_in[3];
  const float* b1   = (const float*)d_in[4];
  const float* W2   = (const float*)d_in[5];
  const float* b2   = (const float*)d_in[6];
  const float* Wih  = (const float*)d_in[7];
  const float* bih  = (const float*)d_in[8];
  const float* Whh  = (const float*)d_in[9];
  const float* bhh  = (const float*)d_in[10];
  const float* Wout = (const float*)d_in[11];
  const float* bout = (const float*)d_in[12];

  float* outp = (float*)d_out;
  float* hT   = outp + (size_t)128 * T_SZ * 64;
  uint32* C   = (uint32*)d_out;                 // ctrl+segs scratch, overwritten by out_gemm

  unsigned short* xg = (unsigned short*)d_ws;                          // 100,663,296 B
  unsigned short* ys = (unsigned short*)((char*)d_ws + 100663296ull);  //  33,554,432 B

  zero_ctrl  <<<dim3(4),    dim3(1024), 0, stream>>>(C);
  seg_pass   <<<dim3(16),   dim3(512),  0, stream>>>(ii, C, 0);
  seg_prefix <<<dim3(1),    dim3(1024), 0, stream>>>(C);
  seg_pass   <<<dim3(16),   dim3(512),  0, stream>>>(ii, C, 1);
  fused_mlp  <<<dim3(512),  dim3(512),  0, stream>>>(x, W1, b1, W2, b2, Wih, bih, xg);
  gru_seg_scan<<<dim3(2048),dim3(512),  0, stream>>>(xg, hx, ii, Whh, bhh, C, ys, hT);
  out_gemm   <<<dim3(2048), dim3(256),  0, stream>>>(ys, Wout, bout, outp);
}

// Round 3
// 330.345 us; speedup vs baseline: 4.6102x; 3.4755x over previous
//
#include <hip/hip_runtime.h>

// GRUModule: MLP(64->128->128,ELU) -> xg=W_ih proj -> segment-parallel GRU(H=128) -> W_out head
// B=128, T=1024. All GEMMs via mfma_f32_16x16x32_bf16.
// ws: [xg bf16 [b][t][384]: 100,663,296 B][ys bf16 [t][g][16][128]: 33,554,432 B] = 128 MiB
// ctrl+segs live in d_out (first ~540 KB), overwritten by out_gemm afterwards.
// R3: seg_pass global-atomic contention (420us x2) -> single seg_build kernel,
//     per-block LDS counting sort + one global atomic per block.

#define T_SZ 1024

typedef __attribute__((ext_vector_type(8))) short short8;
typedef __attribute__((ext_vector_type(4))) float f32x4;
typedef unsigned long long u64;
typedef unsigned int uint32;

__device__ __forceinline__ unsigned short f2b(float f){
  unsigned int u = __builtin_bit_cast(unsigned int, f);
  u += 0x7fffu + ((u >> 16) & 1u);
  return (unsigned short)(u >> 16);
}
__device__ __forceinline__ float b2f(unsigned int hs){
  unsigned int u = hs << 16;
  return __builtin_bit_cast(float, u);
}
__device__ __forceinline__ short8 load_w8(const float* __restrict__ p){
  const float4* q = (const float4*)p;
  float4 u0 = q[0], u1 = q[1];
  short8 v;
  v[0]=(short)f2b(u0.x); v[1]=(short)f2b(u0.y); v[2]=(short)f2b(u0.z); v[3]=(short)f2b(u0.w);
  v[4]=(short)f2b(u1.x); v[5]=(short)f2b(u1.y); v[6]=(short)f2b(u1.z); v[7]=(short)f2b(u1.w);
  return v;
}
__device__ __forceinline__ float elu(float v){ return v > 0.f ? v : __expf(v) - 1.f; }
__device__ __forceinline__ float sigm(float x){ return 1.f / (1.f + __expf(-x)); }
__device__ __forceinline__ float tanh_fast(float x){
  x = fminf(fmaxf(x, -15.f), 15.f);
  float e = __expf(-2.f * x);
  return (1.f - e) / (1.f + e);
}
#define MFMA16(a,b,c) __builtin_amdgcn_mfma_f32_16x16x32_bf16(a, b, c, 0, 0, 0)

// ctrl layout in d_out (as uint32*): [1]=n_tiles [2]=slot cursor; segs = C+4096

// ---------------------------------------------------------------------------
// seg_build: 16 blocks x 512 thr; block owns 8 batch rows. Enumerate reset-
// delimited segments, counting-sort desc-by-length block-locally in LDS,
// reserve a 16-aligned global region with ONE atomicAdd, write sorted segs
// (+ len-0 padding to multiple of 16).
// ---------------------------------------------------------------------------
__global__ __launch_bounds__(512) void seg_build(const int* __restrict__ ii, uint32* C){
  __shared__ uint32 lh[1024];     // counts per key k = 1024-len  (len 1..1024)
  __shared__ uint32 lbase[1024];  // exclusive prefix in k order
  __shared__ uint32 ssum[512];
  __shared__ uint32 sbase;
  uint32* segs = C + 4096;
  const int tid = threadIdx.x;
  const int wv = tid >> 6, lane = tid & 63;
  const int b = blockIdx.x*8 + wv;

  for(int i = tid; i < 1024; i += 512) lh[i] = 0u;
  __syncthreads();

  // enumerate segment starts for row b (one bit per t)
  u64 bal[16];
  #pragma unroll
  for(int c=0;c<16;c++){
    int t = c*64 + lane;
    int m = ii[b*T_SZ + t];
    bal[c] = __ballot((m != 0) || (t == 0));
  }
  int fsA[16]; int nx = T_SZ;
  #pragma unroll
  for(int c=15;c>=0;c--){ fsA[c]=nx; if(bal[c]) nx = c*64 + __builtin_ctzll(bal[c]); }

  int lenA[16], rkA[16];
  #pragma unroll
  for(int c=0;c<16;c++){
    lenA[c] = 0;
    if((bal[c] >> lane) & 1ull){
      int t = c*64 + lane;
      u64 hi = (lane < 63) ? (bal[c] >> (lane+1)) : 0ull;
      int nxt = hi ? (t + 1 + __builtin_ctzll(hi)) : fsA[c];
      int len = nxt - t;
      lenA[c] = len;
      rkA[c] = (int)atomicAdd(&lh[1024 - len], 1u);   // LDS atomic: count + rank
    }
  }
  __syncthreads();

  // exclusive prefix over 1024 bins (k ascending = len descending)
  uint32 c0 = lh[2*tid], c1 = lh[2*tid+1];
  ssum[tid] = c0 + c1;
  __syncthreads();
  #pragma unroll
  for(int off=1; off<512; off<<=1){
    uint32 v = (tid >= off) ? ssum[tid-off] : 0u;
    __syncthreads();
    ssum[tid] += v;
    __syncthreads();
  }
  uint32 excl = tid ? ssum[tid-1] : 0u;
  lbase[2*tid]   = excl;
  lbase[2*tid+1] = excl + c0;
  uint32 total = ssum[511];
  uint32 padded = (total + 15u) & ~15u;
  if(tid == 0){
    sbase = atomicAdd(&C[2], padded);
    atomicAdd(&C[1], padded >> 4);
  }
  __syncthreads();
  const uint32 base = sbase;

  #pragma unroll
  for(int c=0;c<16;c++){
    if(lenA[c] > 0){
      int t = c*64 + lane;
      uint32 slot = base + lbase[1024 - lenA[c]] + (uint32)rkA[c];
      segs[slot] = ((uint32)b << 21) | ((uint32)t << 11) | (uint32)lenA[c];
    }
  }
  for(uint32 i = total + tid; i < padded; i += 512) segs[base + i] = 0u;
}

// ---------------------------------------------------------------------------
// K1: fused MLP1 + MLP2 + W_ih projection. M-tile = (t, g): rows b=16g..16g+15.
// xg output: bf16 [b][t][384] via LDS transpose for coalesced 768B-row writes.
// ---------------------------------------------------------------------------
__global__ __launch_bounds__(512) void fused_mlp(
    const float* __restrict__ x,
    const float* __restrict__ W1, const float* __restrict__ b1,
    const float* __restrict__ W2, const float* __restrict__ b2,
    const float* __restrict__ Wih, const float* __restrict__ bih,
    unsigned short* __restrict__ xg)
{
  __shared__ unsigned short xl[16*72];     // x tile, A-layout [16][64+8]
  __shared__ unsigned short h1l[16*136];
  __shared__ unsigned short h2l[16*136];
  __shared__ unsigned short xgl[16*392];   // [16 rows][384+8] gate staging
  const int tid = threadIdx.x;
  const int wv = tid >> 6, l = tid & 63, quad = l >> 4, col = l & 15;
  const int n = 16*wv + col;

  short8 w1f[2], w2f[4], wif[3][4];
  #pragma unroll
  for(int ks=0; ks<2; ks++) w1f[ks] = load_w8(W1 + n*64  + ks*32 + quad*8);
  #pragma unroll
  for(int ks=0; ks<4; ks++) w2f[ks] = load_w8(W2 + n*128 + ks*32 + quad*8);
  #pragma unroll
  for(int gt=0; gt<3; gt++){
    #pragma unroll
    for(int ks=0; ks<4; ks++)
      wif[gt][ks] = load_w8(Wih + (n + 128*gt)*128 + ks*32 + quad*8);
  }
  const float b1v = b1[n], b2v = b2[n];
  float bihv[3];
  #pragma unroll
  for(int gt=0; gt<3; gt++) bihv[gt] = bih[n + 128*gt];

  for(int tile = blockIdx.x; tile < 8192; tile += gridDim.x){
    const int t = tile >> 3, g = tile & 7;
    __syncthreads();
    for(int i = tid; i < 1024; i += 512){
      int m = i >> 6, k = i & 63;
      xl[m*72 + k] = f2b(x[(size_t)(16*g + m)*(T_SZ*64) + (size_t)t*64 + k]);
    }
    __syncthreads();
    f32x4 acc1 = {b1v, b1v, b1v, b1v};
    #pragma unroll
    for(int ks=0; ks<2; ks++){
      short8 a = *(const short8*)&xl[col*72 + ks*32 + quad*8];
      acc1 = MFMA16(a, w1f[ks], acc1);
    }
    #pragma unroll
    for(int r=0; r<4; r++)
      h1l[(quad*4+r)*136 + n] = f2b(elu(acc1[r]));
    __syncthreads();
    f32x4 acc2 = {b2v, b2v, b2v, b2v};
    #pragma unroll
    for(int ks=0; ks<4; ks++){
      short8 a = *(const short8*)&h1l[col*136 + ks*32 + quad*8];
      acc2 = MFMA16(a, w2f[ks], acc2);
    }
    #pragma unroll
    for(int r=0; r<4; r++)
      h2l[(quad*4+r)*136 + n] = f2b(elu(acc2[r]));
    __syncthreads();
    f32x4 a0 = {bihv[0], bihv[0], bihv[0], bihv[0]};
    f32x4 a1 = {bihv[1], bihv[1], bihv[1], bihv[1]};
    f32x4 a2 = {bihv[2], bihv[2], bihv[2], bihv[2]};
    #pragma unroll
    for(int ks=0; ks<4; ks++){
      short8 a = *(const short8*)&h2l[col*136 + ks*32 + quad*8];
      a0 = MFMA16(a, wif[0][ks], a0);
      a1 = MFMA16(a, wif[1][ks], a1);
      a2 = MFMA16(a, wif[2][ks], a2);
    }
    #pragma unroll
    for(int r=0; r<4; r++){
      int row = quad*4 + r;
      xgl[row*392 +       n] = f2b(a0[r]);
      xgl[row*392 + 128 + n] = f2b(a1[r]);
      xgl[row*392 + 256 + n] = f2b(a2[r]);
    }
    __syncthreads();
    // cooperative coalesced write: 16 rows x 768 B
    {
      const int row = tid >> 5, k = tid & 31;
      unsigned short* dst = xg + ((size_t)(16*g + row)*T_SZ + t)*384;
      const unsigned short* srcl = xgl + row*392;
      #pragma unroll
      for(int i=0; i<3; i++)
        *(u64*)(dst + i*128 + k*4) = *(const u64*)(srcl + i*128 + k*4);
    }
  }
}

// ---------------------------------------------------------------------------
// K2: segment-parallel GRU. One block = tile of 16 segments (block-locally
// sorted desc len; padding entries have len=0). 8 waves: wave wv owns hidden
// cols 16wv..16wv+15 for all 3 gates. xg rows double-buffered through LDS.
// ---------------------------------------------------------------------------
__global__ __launch_bounds__(512) void gru_seg_scan(
    const unsigned short* __restrict__ xg,
    const float* __restrict__ hx, const int* __restrict__ ii,
    const float* __restrict__ Whh, const float* __restrict__ bhh,
    const uint32* __restrict__ C,
    unsigned short* __restrict__ ys, float* __restrict__ hT)
{
  __shared__ unsigned short hl[16*136];          // h, A-layout
  __shared__ unsigned short xbuf[2][16*772];     // xg tile, [16 rows][768+4]
  __shared__ int srb[16], srt[16], srlen[16];
  const int tid = threadIdx.x;
  const int wv = tid >> 6, l = tid & 63, quad = l >> 4, col = l & 15;
  const int nidx = 16*wv + col;
  const int frow = tid >> 5, fk = tid & 31;      // fetch assignment

  const uint32 ntile = C[1];
  const uint32* segs = C + 4096;

  short8 whf[3][4];
  float bhv[3];
  #pragma unroll
  for(int gt=0; gt<3; gt++){
    int n = nidx + 128*gt;
    bhv[gt] = bhh[n];
    #pragma unroll
    for(int ks=0; ks<4; ks++)
      whf[gt][ks] = load_w8(Whh + n*128 + ks*32 + quad*8);
  }

  for(uint32 tile = blockIdx.x; tile < ntile; tile += gridDim.x){
    __syncthreads();                             // protect sr*/hl/xbuf reuse
    if(tid < 16){
      uint32 w = segs[16*tile + (uint32)tid];    // padding entries: w=0 -> len 0
      srb[tid] = (int)(w >> 21);
      srt[tid] = (int)((w >> 11) & 1023u);
      srlen[tid] = (int)(w & 2047u);
    }
    __syncthreads();
    const int maxlen = srlen[0];                 // desc order within tile

    // h0: hx if segment starts at t=0 with no reset, else 0
    float hreg[4];
    #pragma unroll
    for(int r=0; r<4; r++){
      int row = quad*4 + r;
      int b = srb[row];
      bool uh = (srlen[row] > 0) && (srt[row] == 0) && (ii[b*T_SZ] == 0);
      float h0 = uh ? hx[b*128 + nidx] : 0.f;
      hreg[r] = h0;
      hl[row*136 + nidx] = f2b(h0);
    }
    // prologue: fetch xg rows for step 0 into xbuf[0]
    {
      const unsigned short* src = xg + ((size_t)srb[frow]*T_SZ + srt[frow])*384;
      unsigned short* xb = &xbuf[0][frow*772];
      #pragma unroll
      for(int i=0; i<3; i++)
        *(u64*)(xb + i*128 + fk*4) = *(const u64*)(src + i*128 + fk*4);
    }

    int cur = 0;
    for(int i=0; i<maxlen; i++){
      // prefetch step i+1 (clamped) into registers
      u64 p0, p1, p2;
      {
        int rl = srlen[frow];
        int tc = (i+1 < rl) ? i+1 : (rl > 0 ? rl-1 : 0);
        const unsigned short* src = xg + ((size_t)srb[frow]*T_SZ + (srt[frow] + tc))*384;
        p0 = *(const u64*)(src +       fk*4);
        p1 = *(const u64*)(src + 128 + fk*4);
        p2 = *(const u64*)(src + 256 + fk*4);
      }
      __syncthreads();                           // B1: hl(i) + xbuf[cur] ready
      short8 af[4];
      #pragma unroll
      for(int ks=0; ks<4; ks++)
        af[ks] = *(const short8*)&hl[col*136 + ks*32 + quad*8];
      __syncthreads();                           // B2: hl reads done
      f32x4 ar = {bhv[0], bhv[0], bhv[0], bhv[0]};
      f32x4 az = {bhv[1], bhv[1], bhv[1], bhv[1]};
      f32x4 an = {bhv[2], bhv[2], bhv[2], bhv[2]};
      #pragma unroll
      for(int ks=0; ks<4; ks++){
        ar = MFMA16(af[ks], whf[0][ks], ar);
        az = MFMA16(af[ks], whf[1][ks], az);
        an = MFMA16(af[ks], whf[2][ks], an);
      }
      const unsigned short* xb = &xbuf[cur][0];
      #pragma unroll
      for(int r=0; r<4; r++){
        int row = quad*4 + r;
        float xrv = b2f(xb[row*772 +       nidx]);
        float xzv = b2f(xb[row*772 + 128 + nidx]);
        float xnv = b2f(xb[row*772 + 256 + nidx]);
        float rr = sigm(xrv + ar[r]);
        float zz = sigm(xzv + az[r]);
        float nn = tanh_fast(xnv + rr*an[r]);
        float hnew = (1.f - zz)*nn + zz*hreg[r];
        int rl = srlen[row];
        if(i < rl){
          int b = srb[row], t = srt[row] + i;
          ys[((size_t)(t*8 + (b>>4))*16 + (b&15))*128 + nidx] = f2b(hnew);
          if(i == rl-1 && (srt[row] + rl) == T_SZ)
            hT[b*128 + nidx] = hnew;
        }
        hreg[r] = hnew;
        hl[row*136 + nidx] = f2b(hnew);
      }
      // drain prefetch into the other buffer
      {
        unsigned short* xb2 = &xbuf[cur^1][frow*772];
        *(u64*)(xb2 +       fk*4) = p0;
        *(u64*)(xb2 + 128 + fk*4) = p1;
        *(u64*)(xb2 + 256 + fk*4) = p2;
      }
      cur ^= 1;
    }
  }
}

// ---------------------------------------------------------------------------
// K3: out = y @ W_out.T + b_out.
// ---------------------------------------------------------------------------
__global__ __launch_bounds__(256) void out_gemm(
    const unsigned short* __restrict__ ys,
    const float* __restrict__ Wout, const float* __restrict__ bout,
    float* __restrict__ outp)
{
  const int tid = threadIdx.x;
  const int wv = tid >> 6, l = tid & 63, quad = l >> 4, col = l & 15;
  const int n = 16*wv + col;
  short8 wof[4];
  #pragma unroll
  for(int ks=0; ks<4; ks++) wof[ks] = load_w8(Wout + n*128 + ks*32 + quad*8);
  const float bov = bout[n];
  for(int tile = blockIdx.x; tile < 8192; tile += gridDim.x){
    const int t = tile >> 3, g = tile & 7;
    const unsigned short* yt = ys + (size_t)tile * 16 * 128;
    f32x4 acc = {bov, bov, bov, bov};
    #pragma unroll
    for(int ks=0; ks<4; ks++){
      short8 a = *(const short8*)&yt[col*128 + ks*32 + quad*8];
      acc = MFMA16(a, wof[ks], acc);
    }
    #pragma unroll
    for(int r=0; r<4; r++)
      outp[(size_t)(16*g + quad*4 + r)*(T_SZ*64) + (size_t)t*64 + n] = acc[r];
  }
}

extern "C" void kernel_launch(void* const* d_in, const int* in_sizes, int n_in,
                              void* d_out, int out_size, void* d_ws, size_t ws_size,
                              hipStream_t stream)
{
  const float* x    = (const float*)d_in[0];
  const int*   ii   = (const int*)  d_in[1];
  const float* hx   = (const float*)d_in[2];
  const float* W1   = (const float*)d_in[3];
  const float* b1   = (const float*)d_in[4];
  const float* W2   = (const float*)d_in[5];
  const float* b2   = (const float*)d_in[6];
  const float* Wih  = (const float*)d_in[7];
  const float* bih  = (const float*)d_in[8];
  const float* Whh  = (const float*)d_in[9];
  const float* bhh  = (const float*)d_in[10];
  const float* Wout = (const float*)d_in[11];
  const float* bout = (const float*)d_in[12];

  float* outp = (float*)d_out;
  float* hT   = outp + (size_t)128 * T_SZ * 64;
  uint32* C   = (uint32*)d_out;                 // ctrl+segs scratch, overwritten by out_gemm

  unsigned short* xg = (unsigned short*)d_ws;                          // 100,663,296 B
  unsigned short* ys = (unsigned short*)((char*)d_ws + 100663296ull);  //  33,554,432 B

  hipMemsetAsync(C, 0, 64, stream);             // C[0..15] = 0 (ntile, cursor)
  seg_build  <<<dim3(16),   dim3(512),  0, stream>>>(ii, C);
  fused_mlp  <<<dim3(512),  dim3(512),  0, stream>>>(x, W1, b1, W2, b2, Wih, bih, xg);
  gru_seg_scan<<<dim3(2048),dim3(512),  0, stream>>>(xg, hx, ii, Whh, bhh, C, ys, hT);
  out_gemm   <<<dim3(2048), dim3(256),  0, stream>>>(ys, Wout, bout, outp);
}